// Round 2
// baseline (154.244 us; speedup 1.0000x reference)
//
#include <hip/hip_runtime.h>
#include <hip/hip_bf16.h>
#include <math.h>

#define NROW 8192
#define DD   128
#define NT   64            // tiles per dim
#define TS   128           // tile size
#define NPAIR 2080         // NT*(NT+1)/2
#define BLOCK 512

#define LOG_2PI 1.8378770664093453f
#define L2E     1.4426950408889634f
#define FP_SCALE 1099511627776.0   // 2^40

typedef __attribute__((ext_vector_type(8))) short bf16x8;
typedef __attribute__((ext_vector_type(4))) float f32x4;

// ---- ws byte layout ----
#define ACC_B   0                       // 8192*3*8 = 196608 B (i64 fixed-point sums)
#define SQX_B   196608                  // 8192 f32
#define SQY_B   229376                  // 8192 f32
#define BSUM_B  262144                  // 64 f32
#define XB_B    262400                  // 8192*128 bf16 = 2 MB
#define YB_B    (262400 + 2097152)
#define WS_PRE_NEED (262400 + 2*2097152)
#define WS_MIN_NEED 262400

__device__ __forceinline__ unsigned short f2bf(float f) {
    unsigned int x = __float_as_uint(f);
    unsigned int r = (x + 0x7fffu + ((x >> 16) & 1u)) >> 16;  // RNE
    return (unsigned short)r;
}

// ---------------- row squared norms (+ optional bf16 precopy) ----------------
template <bool PRE>
__global__ void sq_kernel(const float* __restrict__ X, const float* __restrict__ Y,
                          float* __restrict__ sqx, float* __restrict__ sqy,
                          unsigned short* __restrict__ XB, unsigned short* __restrict__ YB) {
    int tid  = threadIdx.x;
    int rowg = blockIdx.x * 8 + (tid >> 5);   // 0..16383 (X rows then Y rows)
    int lane = tid & 31;
    bool isX = rowg < NROW;
    const float* src = isX ? (X + (size_t)rowg * DD) : (Y + (size_t)(rowg - NROW) * DD);
    float4 v = reinterpret_cast<const float4*>(src)[lane];
    if (PRE) {
        unsigned int w0 = (unsigned int)f2bf(v.x) | ((unsigned int)f2bf(v.y) << 16);
        unsigned int w1 = (unsigned int)f2bf(v.z) | ((unsigned int)f2bf(v.w) << 16);
        unsigned short* dst = (isX ? XB + (size_t)rowg * DD
                                   : YB + (size_t)(rowg - NROW) * DD) + lane * 4;
        uint2 pk; pk.x = w0; pk.y = w1;
        *reinterpret_cast<uint2*>(dst) = pk;
    }
    float s = v.x * v.x + v.y * v.y + v.z * v.z + v.w * v.w;
#pragma unroll
    for (int m = 16; m; m >>= 1) s += __shfl_xor(s, m, 64);
    if (lane == 0) {
        if (isX) sqx[rowg] = s;
        else     sqy[rowg - NROW] = s;
    }
}

// ---------------- fused combine + dual reduction ----------------
template <bool SAME>
__device__ __forceinline__ void combine_reduce(
        const f32x4 (&ax)[4][2], const f32x4 (&ay)[4][2],
        const float (&sq)[4][TS],
        float (&rowred)[4][TS][3], float (&colred)[2][TS][3],
        int wr, int wc, int lane, float cx2, float cy2, float cj2) {
    float pcol[2][3] = {{0.f,0.f,0.f},{0.f,0.f,0.f}};
#pragma unroll
    for (int rf = 0; rf < 4; ++rf) {
        float prow[4][3] = {{0.f,0.f,0.f},{0.f,0.f,0.f},{0.f,0.f,0.f},{0.f,0.f,0.f}};
        float sxi[4], syi[4];
#pragma unroll
        for (int reg = 0; reg < 4; ++reg) {
            int row = wr*64 + rf*16 + ((lane>>4)<<2) + reg;
            sxi[reg] = sq[0][row]; syi[reg] = sq[1][row];
        }
#pragma unroll
        for (int cf = 0; cf < 2; ++cf) {
            int col = wc*32 + cf*16 + (lane & 15);
            float qx = sq[2][col], qy = sq[3][col];
#pragma unroll
            for (int reg = 0; reg < 4; ++reg) {
                float gx = ax[rf][cf][reg], gy = ay[rf][cf][reg];
                float d2x = fmaxf(fmaf(-2.f, gx, sxi[reg] + qx), 0.f);
                float d2y = fmaxf(fmaf(-2.f, gy, syi[reg] + qy), 0.f);
                float ex = exp2f(d2x * cx2);
                float ey = exp2f(d2y * cy2);
                float ej = SAME ? (ex * ey) : exp2f(fmaf(d2y, cj2, d2x * cj2));
                prow[reg][0] += ex; prow[reg][1] += ey; prow[reg][2] += ej;
                pcol[cf][0]  += ex; pcol[cf][1]  += ey; pcol[cf][2]  += ej;
            }
        }
#pragma unroll
        for (int reg = 0; reg < 4; ++reg)
#pragma unroll
            for (int ch = 0; ch < 3; ++ch) {
                float v = prow[reg][ch];
                v += __shfl_xor(v, 1, 64);
                v += __shfl_xor(v, 2, 64);
                v += __shfl_xor(v, 4, 64);
                v += __shfl_xor(v, 8, 64);
                if ((lane & 15) == 0)
                    rowred[wc][wr*64 + rf*16 + ((lane>>4)<<2) + reg][ch] = v;
            }
    }
#pragma unroll
    for (int cf = 0; cf < 2; ++cf)
#pragma unroll
        for (int ch = 0; ch < 3; ++ch) {
            float v = pcol[cf][ch];
            v += __shfl_xor(v, 16, 64);
            v += __shfl_xor(v, 32, 64);
            if (lane < 16) colred[wr][wc*32 + cf*16 + lane][ch] = v;
        }
}

// ---------------- main symmetric-tile kernel ----------------
template <bool PRE>
__launch_bounds__(BLOCK)
__global__ void kde_main(const float* __restrict__ X, const float* __restrict__ Y,
                         const unsigned short* __restrict__ XB, const unsigned short* __restrict__ YB,
                         const float* __restrict__ sjp, const float* __restrict__ sxp,
                         const float* __restrict__ syp,
                         unsigned long long* __restrict__ acc,
                         const float* __restrict__ sqx, const float* __restrict__ sqy) {
    __shared__ unsigned short T[4][TS][DD];    // 128 KB: Xi,Yi,Xj,Yj (bf16, 16B-slot XOR swizzle)
    __shared__ float sq[4][TS];                // sqix, sqiy, sqjx, sqjy
    __shared__ float rowred[4][TS][3];
    __shared__ float colred[2][TS][3];

    const int tid  = threadIdx.x;
    const int lane = tid & 63;
    const int wid  = tid >> 6;
    const int wr   = wid >> 2;      // 0..1  (64-row band)
    const int wc   = wid & 3;       // 0..3  (32-col band)

    // XCD-bijective swizzle (2080 = 8*260), then upper-triangle unrank
    int b = (blockIdx.x & 7) * (NPAIR / 8) + (blockIdx.x >> 3);
    int ti = 0, rem = b;
    while (rem >= NT - ti) { rem -= NT - ti; ++ti; }
    int tj = ti + rem;
    const int i0 = ti * TS, j0 = tj * TS;

    const float sxv = *sxp, syv = *syp, sjv = *sjp;
    const float cx2 = -0.5f * L2E / (sxv * sxv);
    const float cy2 = -0.5f * L2E / (syv * syv);
    const float cj2 = -0.5f * L2E / (sjv * sjv);
    const bool samesig = (cx2 == cy2) && (cy2 == cj2);

    // ---- stage 4 tiles ----
    if (PRE) {
        const int ta = wid >> 1;   // wave-uniform: 0 Xi, 1 Yi, 2 Xj, 3 Yj
        const unsigned short* gb =
            (ta == 0) ? XB + (size_t)i0 * DD :
            (ta == 1) ? YB + (size_t)i0 * DD :
            (ta == 2) ? XB + (size_t)j0 * DD : YB + (size_t)j0 * DD;
        const int rbase = (wid & 1) * 64;
#pragma unroll
        for (int cc = 0; cc < 16; ++cc) {
            int r0  = rbase + cc * 4;                // wave-uniform
            int row = r0 + (lane >> 4);
            int sl  = (lane & 15) ^ (row & 7);       // pre-swizzled SOURCE (m173)
            const unsigned short* g = gb + row * DD + sl * 8;
            __builtin_amdgcn_global_load_lds(
                (const __attribute__((address_space(1))) unsigned int*)g,
                (__attribute__((address_space(3))) unsigned int*)&T[ta][r0][0],
                16, 0, 0);
        }
    } else {
        for (int c = tid; c < 8192; c += BLOCK) {
            int t = c >> 11, row = (c >> 4) & 127, col8 = c & 15;
            const float* base =
                (t == 0) ? X + (size_t)i0 * DD :
                (t == 1) ? Y + (size_t)i0 * DD :
                (t == 2) ? X + (size_t)j0 * DD : Y + (size_t)j0 * DD;
            const float4* s4 = reinterpret_cast<const float4*>(base + row * DD + col8 * 8);
            float4 a = s4[0], bb = s4[1];
            unsigned int w0 = (unsigned int)f2bf(a.x)  | ((unsigned int)f2bf(a.y)  << 16);
            unsigned int w1 = (unsigned int)f2bf(a.z)  | ((unsigned int)f2bf(a.w)  << 16);
            unsigned int w2 = (unsigned int)f2bf(bb.x) | ((unsigned int)f2bf(bb.y) << 16);
            unsigned int w3 = (unsigned int)f2bf(bb.z) | ((unsigned int)f2bf(bb.w) << 16);
            uint4 pk = make_uint4(w0, w1, w2, w3);
            int sl = (col8 ^ (row & 7)) << 3;
            *reinterpret_cast<uint4*>(&T[t][row][sl]) = pk;
        }
    }
    {   // sq staging: 512 threads, one entry each
        int t = tid >> 7, r = tid & 127;
        const float* s = (t == 0) ? sqx + i0 : (t == 1) ? sqy + i0
                       : (t == 2) ? sqx + j0 : sqy + j0;
        sq[t][r] = s[r];
    }
    __syncthreads();

    // ---- two GEMMs: Gx = Xi·Xj^T, Gy = Yi·Yj^T ----
    f32x4 ax[4][2], ay[4][2];
#pragma unroll
    for (int rf = 0; rf < 4; ++rf)
#pragma unroll
        for (int cf = 0; cf < 2; ++cf) {
            ax[rf][cf] = (f32x4){0.f, 0.f, 0.f, 0.f};
            ay[rf][cf] = (f32x4){0.f, 0.f, 0.f, 0.f};
        }

#pragma unroll
    for (int kk = 0; kk < 4; ++kk) {
        const int k0 = kk * 4 + (lane >> 4);
        bf16x8 afx[4], afy[4], bfx[2], bfy[2];
#pragma unroll
        for (int rf = 0; rf < 4; ++rf) {
            int r  = wr * 64 + rf * 16 + (lane & 15);
            int sl = (k0 ^ (r & 7)) << 3;
            afx[rf] = *reinterpret_cast<const bf16x8*>(&T[0][r][sl]);
            afy[rf] = *reinterpret_cast<const bf16x8*>(&T[1][r][sl]);
        }
#pragma unroll
        for (int cf = 0; cf < 2; ++cf) {
            int r  = wc * 32 + cf * 16 + (lane & 15);
            int sl = (k0 ^ (r & 7)) << 3;
            bfx[cf] = *reinterpret_cast<const bf16x8*>(&T[2][r][sl]);
            bfy[cf] = *reinterpret_cast<const bf16x8*>(&T[3][r][sl]);
        }
#pragma unroll
        for (int rf = 0; rf < 4; ++rf)
#pragma unroll
            for (int cf = 0; cf < 2; ++cf) {
                ax[rf][cf] = __builtin_amdgcn_mfma_f32_16x16x32_bf16(afx[rf], bfx[cf], ax[rf][cf], 0, 0, 0);
                ay[rf][cf] = __builtin_amdgcn_mfma_f32_16x16x32_bf16(afy[rf], bfy[cf], ay[rf][cf], 0, 0, 0);
            }
    }

    // ---- combine (uniform branch on sigma equality) ----
    if (samesig) combine_reduce<true >(ax, ay, sq, rowred, colred, wr, wc, lane, cx2, cy2, cj2);
    else         combine_reduce<false>(ax, ay, sq, rowred, colred, wr, wc, lane, cx2, cy2, cj2);
    __syncthreads();

    // ---- fixed-point atomic scatter (exact i64 adds -> deterministic) ----
    if (tid < TS) {
        int r = tid;
#pragma unroll
        for (int ch = 0; ch < 3; ++ch) {
            float v = rowred[0][r][ch] + rowred[1][r][ch] + rowred[2][r][ch] + rowred[3][r][ch];
            unsigned long long q = (unsigned long long)(long long)((double)v * FP_SCALE);
            atomicAdd(&acc[(size_t)(i0 + r) * 3 + ch], q);
        }
    } else if (tid < 2 * TS && ti != tj) {
        int r = tid - TS;
#pragma unroll
        for (int ch = 0; ch < 3; ++ch) {
            float v = colred[0][r][ch] + colred[1][r][ch];
            unsigned long long q = (unsigned long long)(long long)((double)v * FP_SCALE);
            atomicAdd(&acc[(size_t)(j0 + r) * 3 + ch], q);
        }
    }
}

// ---------------- per-row lp + partial loss ----------------
__global__ void lp_reduce(const float* __restrict__ sjp, const float* __restrict__ sxp,
                          const float* __restrict__ syp,
                          const unsigned long long* __restrict__ acc,
                          float* __restrict__ bsum) {
    int b = blockIdx.x;    // 64 blocks, 128 rows each
    int t = threadIdx.x;   // 128 threads
    size_t row = (size_t)b * 128 + t;
    const double INV = 1.0 / FP_SCALE;
    float Sx = (float)((double)acc[row * 3 + 0] * INV);
    float Sy = (float)((double)acc[row * 3 + 1] * INV);
    float Sj = (float)((double)acc[row * 3 + 2] * INV);
    float sx = *sxp, sy = *syp, sj = *sjp;
    float logN = logf((float)NROW);
    float lpx = logf(Sx) - (float)DD * logf(sx) - 0.5f * (float)DD * LOG_2PI - logN;
    float lpy = logf(Sy) - (float)DD * logf(sy) - 0.5f * (float)DD * LOG_2PI - logN;
    float lpj = logf(Sj) - 2.0f * (float)DD * logf(sj) - (float)DD * LOG_2PI - logN;
    float I = expf(lpj) * (lpj - lpx - lpy);
#pragma unroll
    for (int m = 1; m < 64; m <<= 1) I += __shfl_xor(I, m, 64);
    __shared__ float w0[2];
    if ((t & 63) == 0) w0[t >> 6] = I;
    __syncthreads();
    if (t == 0) bsum[b] = w0[0] + w0[1];
}

__global__ void final_reduce(const float* __restrict__ bsum, float* __restrict__ out) {
    int t = threadIdx.x;   // 64
    float v = bsum[t];
#pragma unroll
    for (int m = 1; m < 64; m <<= 1) v += __shfl_xor(v, m, 64);
    if (t == 0) out[0] = -v;
}

extern "C" void kernel_launch(void* const* d_in, const int* in_sizes, int n_in,
                              void* d_out, int out_size, void* d_ws, size_t ws_size,
                              hipStream_t stream) {
    (void)in_sizes; (void)n_in; (void)out_size;
    const float* X  = (const float*)d_in[0];
    const float* Y  = (const float*)d_in[1];
    const float* sj = (const float*)d_in[2];
    const float* sx = (const float*)d_in[3];
    const float* sy = (const float*)d_in[4];
    float* out = (float*)d_out;
    char*  w   = (char*)d_ws;

    unsigned long long* ACC = (unsigned long long*)(w + ACC_B);
    float* SQX  = (float*)(w + SQX_B);
    float* SQY  = (float*)(w + SQY_B);
    float* BSUM = (float*)(w + BSUM_B);
    unsigned short* XB = (unsigned short*)(w + XB_B);
    unsigned short* YB = (unsigned short*)(w + YB_B);

    // zero the fixed-point accumulators every call (graph replays re-zero)
    hipMemsetAsync(w + ACC_B, 0, NROW * 3 * sizeof(unsigned long long), stream);

    if (ws_size >= (size_t)WS_PRE_NEED) {
        sq_kernel<true ><<<dim3(2048), dim3(256), 0, stream>>>(X, Y, SQX, SQY, XB, YB);
        kde_main<true ><<<dim3(NPAIR), dim3(BLOCK), 0, stream>>>(X, Y, XB, YB, sj, sx, sy, ACC, SQX, SQY);
    } else {
        sq_kernel<false><<<dim3(2048), dim3(256), 0, stream>>>(X, Y, SQX, SQY, XB, YB);
        kde_main<false><<<dim3(NPAIR), dim3(BLOCK), 0, stream>>>(X, Y, XB, YB, sj, sx, sy, ACC, SQX, SQY);
    }
    lp_reduce<<<dim3(64), dim3(128), 0, stream>>>(sj, sx, sy, ACC, BSUM);
    final_reduce<<<dim3(1), dim3(64), 0, stream>>>(BSUM, out);
}

// Round 3
// 142.305 us; speedup vs baseline: 1.0839x; 1.0839x over previous
//
#include <hip/hip_runtime.h>
#include <hip/hip_bf16.h>
#include <math.h>

#define NROW 8192
#define DD   128
#define NT   64
#define TS   128
#define NPAIR 2080
#define BLOCK 512
#define NBLOCKS 256

#define LOG_2PI 1.8378770664093453f
#define L2E     1.4426950408889634f
#define FP_SCALE 1099511627776.0   // 2^40

typedef __attribute__((ext_vector_type(8))) short bf16x8;
typedef __attribute__((ext_vector_type(4))) float f32x4;

// ---- ws byte layout ----
#define ACC_B   0                        // 8192*3*8 = 196608
#define SQX_B   196608
#define SQY_B   229376
#define BSUM_B  262144
#define COLSLOT_B 262400                 // NPAIR*3*128*4 = 3194880
#define XB_B    (COLSLOT_B + NPAIR*3*128*4)      // 3457280
#define YB_B    (XB_B + NROW*DD*2)
#define PRIMARY_NEED (YB_B + NROW*DD*2)          // ~7.65 MB
#define FB_NEED 262400

__device__ __forceinline__ unsigned short f2bf(float f) {
    unsigned int x = __float_as_uint(f);
    unsigned int r = (x + 0x7fffu + ((x >> 16) & 1u)) >> 16;  // RNE
    return (unsigned short)r;
}
__device__ __forceinline__ int rankbase(int ti) { return ti * 64 - (ti * (ti - 1)) / 2; }
__device__ __forceinline__ float fexp2(float x) { return __builtin_amdgcn_exp2f(x); }

// ---------------- row squared norms (+ optional bf16 precopy) ----------------
template <bool PRE>
__global__ void sq_kernel(const float* __restrict__ X, const float* __restrict__ Y,
                          float* __restrict__ sqx, float* __restrict__ sqy,
                          unsigned short* __restrict__ XB, unsigned short* __restrict__ YB) {
    int tid  = threadIdx.x;
    int rowg = blockIdx.x * 8 + (tid >> 5);
    int lane = tid & 31;
    bool isX = rowg < NROW;
    const float* src = isX ? (X + (size_t)rowg * DD) : (Y + (size_t)(rowg - NROW) * DD);
    float4 v = reinterpret_cast<const float4*>(src)[lane];
    if (PRE) {
        unsigned int w0 = (unsigned int)f2bf(v.x) | ((unsigned int)f2bf(v.y) << 16);
        unsigned int w1 = (unsigned int)f2bf(v.z) | ((unsigned int)f2bf(v.w) << 16);
        unsigned short* dst = (isX ? XB + (size_t)rowg * DD
                                   : YB + (size_t)(rowg - NROW) * DD) + lane * 4;
        uint2 pk; pk.x = w0; pk.y = w1;
        *reinterpret_cast<uint2*>(dst) = pk;
    }
    float s = v.x * v.x + v.y * v.y + v.z * v.z + v.w * v.w;
#pragma unroll
    for (int m = 16; m; m >>= 1) s += __shfl_xor(s, m, 64);
    if (lane == 0) { if (isX) sqx[rowg] = s; else sqy[rowg - NROW] = s; }
}

// ================= PRIMARY =================

// stage one j-tile (both mats, 64KB) + its sq row (1KB) into LDS via global_load_lds
__device__ __forceinline__ void stage_tile(const unsigned short* __restrict__ XBp,
                                           const unsigned short* __restrict__ YBp,
                                           const float* __restrict__ sqx,
                                           const float* __restrict__ sqy,
                                           int tj, int wid, int lane,
                                           unsigned short (*buf)[TS][DD], float (*sqj)[TS]) {
    const unsigned short* gb = (wid >> 2) ? YBp : XBp;
    const unsigned short* base = gb + (size_t)(tj * TS) * DD;
    const int mat = wid >> 2;
    const int rq  = (wid & 3) * 32;
#pragma unroll
    for (int i = 0; i < 8; ++i) {
        int rr  = rq + i * 4;
        int row = rr + (lane >> 4);
        int sl  = (lane & 15) ^ (row & 7);          // pre-swizzled SOURCE (m173)
        const unsigned short* g = base + row * DD + sl * 8;
        __builtin_amdgcn_global_load_lds(
            (const __attribute__((address_space(1))) unsigned int*)g,
            (__attribute__((address_space(3))) unsigned int*)&buf[mat][rr][0], 16, 0, 0);
    }
    if (wid == 0) {
        const float* g = (lane < 32) ? (sqx + tj * TS + lane * 4)
                                     : (sqy + tj * TS + (lane - 32) * 4);
        __builtin_amdgcn_global_load_lds(
            (const __attribute__((address_space(1))) unsigned int*)g,
            (__attribute__((address_space(3))) unsigned int*)&sqj[0][0], 16, 0, 0);
    }
}

__device__ __forceinline__ void load_A(const unsigned short* __restrict__ XBp,
                                       const unsigned short* __restrict__ YBp,
                                       const float* __restrict__ sqx,
                                       const float* __restrict__ sqy,
                                       int i0, int wr, int lane,
                                       bf16x8 (&afx)[2][4], bf16x8 (&afy)[2][4],
                                       float (&sxi)[2][4], float (&syi)[2][4]) {
#pragma unroll
    for (int rf = 0; rf < 2; ++rf) {
        int rowa = i0 + wr * 32 + rf * 16 + (lane & 15);
#pragma unroll
        for (int kk = 0; kk < 4; ++kk) {
            size_t off = (size_t)rowa * DD + kk * 32 + (lane >> 4) * 8;
            afx[rf][kk] = *reinterpret_cast<const bf16x8*>(XBp + off);
            afy[rf][kk] = *reinterpret_cast<const bf16x8*>(YBp + off);
        }
#pragma unroll
        for (int reg = 0; reg < 4; ++reg) {
            int rowc = i0 + wr * 32 + rf * 16 + ((lane >> 4) << 2) + reg;
            sxi[rf][reg] = sqx[rowc];
            syi[rf][reg] = sqy[rowc];
        }
    }
}

// MODE bit0: diagonal tile, bit1: sigmas differ
template <int MODE>
__device__ __forceinline__ void combine_tile(const f32x4 (&ax)[2][4], const f32x4 (&ay)[2][4],
                                             const float (&sxi)[2][4], const float (&syi)[2][4],
                                             const float* __restrict__ sqjx,
                                             const float* __restrict__ sqjy,
                                             float (&prow)[2][4][3], float (&pcol)[4][3],
                                             int wr, int wc, int lane,
                                             float cx2, float cy2, float cj2) {
#pragma unroll
    for (int cf = 0; cf < 4; ++cf) {
        int col = wc * 64 + cf * 16 + (lane & 15);
        float qx = sqjx[col], qy = sqjy[col];
#pragma unroll
        for (int rf = 0; rf < 2; ++rf) {
#pragma unroll
            for (int reg = 0; reg < 4; ++reg) {
                float gx = ax[rf][cf][reg], gy = ay[rf][cf][reg];
                float d2x = fmaf(-2.f, gx, sxi[rf][reg] + qx);
                float d2y = fmaf(-2.f, gy, syi[rf][reg] + qy);
                float ex = fexp2(d2x * cx2);
                float ey = fexp2(d2y * cy2);
                float ej;
                if (MODE & 2) ej = fexp2((d2x + d2y) * cj2);
                else          ej = ex * ey;
                if (MODE & 1) {   // exact diagonal: d2_ii == 0
                    int rowl = wr * 32 + rf * 16 + ((lane >> 4) << 2) + reg;
                    bool dg = (rowl == col);
                    ex = dg ? 1.f : ex;  ey = dg ? 1.f : ey;
                    if (MODE & 2) ej = dg ? 1.f : ej; else ej = ex * ey;
                }
                prow[rf][reg][0] += ex; prow[rf][reg][1] += ey; prow[rf][reg][2] += ej;
                pcol[cf][0] += ex;      pcol[cf][1] += ey;      pcol[cf][2] += ej;
            }
        }
    }
}

__launch_bounds__(BLOCK, 2)
__global__ void kde_primary(const unsigned short* __restrict__ XB,
                            const unsigned short* __restrict__ YB,
                            const float* __restrict__ sjp, const float* __restrict__ sxp,
                            const float* __restrict__ syp,
                            unsigned long long* __restrict__ acc,
                            float* __restrict__ COL,
                            const float* __restrict__ sqx, const float* __restrict__ sqy) {
    __shared__ unsigned short buf[2][2][TS][DD];   // 128 KB (dbuf × {X,Y})
    __shared__ float sqj[2][2][TS];                // 2 KB
    __shared__ float colred[2][4][TS][3];          // 12 KB
    __shared__ float rowred[2][TS][3];             // 3 KB

    const int tid  = threadIdx.x;
    const int lane = tid & 63;
    const int wid  = tid >> 6;
    const int wr   = wid >> 1;     // 0..3  (32-row band)
    const int wc   = wid & 1;      // 0..1  (64-col half)

    const int g  = blockIdx.x;
    const int k  = (g & 7) * 32 + (g >> 3);        // XCD-contiguous chunks (256 = 8*32)
    const int r0 = (65 * k) >> 3;
    const int r1 = (65 * (k + 1)) >> 3;

    const float sxv = *sxp, syv = *syp, sjv = *sjp;
    const float cx2 = -0.5f * L2E / (sxv * sxv);
    const float cy2 = -0.5f * L2E / (syv * syv);
    const float cj2 = -0.5f * L2E / (sjv * sjv);
    const bool samesig = (cx2 == cy2) && (cy2 == cj2);

    int ti = 0;
    while (rankbase(ti + 1) <= r0) ++ti;
    int tj = ti + (r0 - rankbase(ti));
    int i0 = ti * TS;

    bf16x8 afx[2][4], afy[2][4];
    float sxi[2][4], syi[2][4];
    load_A(XB, YB, sqx, sqy, i0, wr, lane, afx, afy, sxi, syi);

    float prow[2][4][3];
#pragma unroll
    for (int a = 0; a < 2; ++a)
#pragma unroll
        for (int b = 0; b < 4; ++b)
#pragma unroll
            for (int c = 0; c < 3; ++c) prow[a][b][c] = 0.f;

    stage_tile(XB, YB, sqx, sqy, tj, wid, lane, buf[0], sqj[0]);
    __syncthreads();

    int pb = 0;
    int prevRank = -1;
    bool prevDiag = true;

    for (int r = r0; r < r1; ++r) {
        const bool last = (r + 1 >= r1);
        int tin = ti, tjn = tj;
        if (!last) {
            if (tj == NT - 1) { tin = ti + 1; tjn = tin; } else { tjn = tj + 1; }
            stage_tile(XB, YB, sqx, sqy, tjn, wid, lane, buf[pb ^ 1], sqj[pb ^ 1]);
        }

        // ---- MFMA on buf[pb] ----
        f32x4 ax[2][4], ay[2][4];
#pragma unroll
        for (int rf = 0; rf < 2; ++rf)
#pragma unroll
            for (int cf = 0; cf < 4; ++cf) {
                ax[rf][cf] = (f32x4){0.f, 0.f, 0.f, 0.f};
                ay[rf][cf] = (f32x4){0.f, 0.f, 0.f, 0.f};
            }
#pragma unroll
        for (int kk = 0; kk < 4; ++kk) {
            bf16x8 bfx[4], bfy[4];
#pragma unroll
            for (int cf = 0; cf < 4; ++cf) {
                int rb  = wc * 64 + cf * 16 + (lane & 15);
                int sll = (kk * 4 + (lane >> 4)) ^ (rb & 7);
                bfx[cf] = *reinterpret_cast<const bf16x8*>(&buf[pb][0][rb][sll * 8]);
                bfy[cf] = *reinterpret_cast<const bf16x8*>(&buf[pb][1][rb][sll * 8]);
            }
#pragma unroll
            for (int cf = 0; cf < 4; ++cf)
#pragma unroll
                for (int rf = 0; rf < 2; ++rf) {
                    ax[rf][cf] = __builtin_amdgcn_mfma_f32_16x16x32_bf16(afx[rf][kk], bfx[cf], ax[rf][cf], 0, 0, 0);
                    ay[rf][cf] = __builtin_amdgcn_mfma_f32_16x16x32_bf16(afy[rf][kk], bfy[cf], ay[rf][cf], 0, 0, 0);
                }
        }

        // ---- combine ----
        float pcol[4][3];
#pragma unroll
        for (int a = 0; a < 4; ++a)
#pragma unroll
            for (int c = 0; c < 3; ++c) pcol[a][c] = 0.f;

        const bool diag = (ti == tj);
        if (samesig) { if (diag) combine_tile<1>(ax, ay, sxi, syi, &sqj[pb][0][0], &sqj[pb][1][0], prow, pcol, wr, wc, lane, cx2, cy2, cj2);
                       else      combine_tile<0>(ax, ay, sxi, syi, &sqj[pb][0][0], &sqj[pb][1][0], prow, pcol, wr, wc, lane, cx2, cy2, cj2); }
        else         { if (diag) combine_tile<3>(ax, ay, sxi, syi, &sqj[pb][0][0], &sqj[pb][1][0], prow, pcol, wr, wc, lane, cx2, cy2, cj2);
                       else      combine_tile<2>(ax, ay, sxi, syi, &sqj[pb][0][0], &sqj[pb][1][0], prow, pcol, wr, wc, lane, cx2, cy2, cj2); }

        // ---- per-tile col reduction into colred[pb] ----
#pragma unroll
        for (int cf = 0; cf < 4; ++cf)
#pragma unroll
            for (int ch = 0; ch < 3; ++ch) {
                float v = pcol[cf][ch];
                v += __shfl_xor(v, 16, 64);
                v += __shfl_xor(v, 32, 64);
                if (lane < 16) colred[pb][wr][wc * 64 + cf * 16 + lane][ch] = v;
            }

        // ---- flush previous tile's col partials (overlaps with this tile's work) ----
        if (prevRank >= 0 && !prevDiag && tid < 384) {
            int ch = tid >> 7, col = tid & 127;
            float v = colred[pb ^ 1][0][col][ch] + colred[pb ^ 1][1][col][ch]
                    + colred[pb ^ 1][2][col][ch] + colred[pb ^ 1][3][col][ch];
            COL[((size_t)prevRank * 3 + ch) * 128 + col] = v;
        }
        prevRank = r;
        prevDiag = diag;
        __syncthreads();

        if (!last) {
            if (tin != ti) {
                // ---- flush row partials for old i-tile ----
#pragma unroll
                for (int rf = 0; rf < 2; ++rf)
#pragma unroll
                    for (int reg = 0; reg < 4; ++reg)
#pragma unroll
                        for (int ch = 0; ch < 3; ++ch) {
                            float v = prow[rf][reg][ch];
                            v += __shfl_xor(v, 1, 64);
                            v += __shfl_xor(v, 2, 64);
                            v += __shfl_xor(v, 4, 64);
                            v += __shfl_xor(v, 8, 64);
                            if ((lane & 15) == 0)
                                rowred[wc][wr * 32 + rf * 16 + ((lane >> 4) << 2) + reg][ch] = v;
                            prow[rf][reg][ch] = 0.f;
                        }
                __syncthreads();
                if (tid < 384) {
                    int ch = tid >> 7, row = tid & 127;
                    double val = (double)(rowred[0][row][ch] + rowred[1][row][ch]);
                    atomicAdd(&acc[(size_t)(i0 + row) * 3 + ch],
                              (unsigned long long)(long long)(val * FP_SCALE));
                }
                ti = tin; i0 = ti * TS;
                load_A(XB, YB, sqx, sqy, i0, wr, lane, afx, afy, sxi, syi);
            }
            tj = tjn;
        }
        pb ^= 1;
    }

    // ---- tail: last tile's col partials + final row flush ----
    if (!prevDiag && tid < 384) {
        int ch = tid >> 7, col = tid & 127;
        float v = colred[pb ^ 1][0][col][ch] + colred[pb ^ 1][1][col][ch]
                + colred[pb ^ 1][2][col][ch] + colred[pb ^ 1][3][col][ch];
        COL[((size_t)prevRank * 3 + ch) * 128 + col] = v;
    }
#pragma unroll
    for (int rf = 0; rf < 2; ++rf)
#pragma unroll
        for (int reg = 0; reg < 4; ++reg)
#pragma unroll
            for (int ch = 0; ch < 3; ++ch) {
                float v = prow[rf][reg][ch];
                v += __shfl_xor(v, 1, 64);
                v += __shfl_xor(v, 2, 64);
                v += __shfl_xor(v, 4, 64);
                v += __shfl_xor(v, 8, 64);
                if ((lane & 15) == 0)
                    rowred[wc][wr * 32 + rf * 16 + ((lane >> 4) << 2) + reg][ch] = v;
            }
    __syncthreads();
    if (tid < 384) {
        int ch = tid >> 7, row = tid & 127;
        double val = (double)(rowred[0][row][ch] + rowred[1][row][ch]);
        atomicAdd(&acc[(size_t)(i0 + row) * 3 + ch],
                  (unsigned long long)(long long)(val * FP_SCALE));
    }
}

__global__ void lp_primary(const float* __restrict__ sjp, const float* __restrict__ sxp,
                           const float* __restrict__ syp,
                           const unsigned long long* __restrict__ acc,
                           const float* __restrict__ COL,
                           float* __restrict__ bsum) {
    int b = blockIdx.x;    // row-tile
    int t = threadIdx.x;   // 128
    size_t row = (size_t)b * 128 + t;
    const double INV = 1.0 / FP_SCALE;
    float S0 = (float)((double)acc[row * 3 + 0] * INV);
    float S1 = (float)((double)acc[row * 3 + 1] * INV);
    float S2 = (float)((double)acc[row * 3 + 2] * INV);
    for (int ti = 0; ti < b; ++ti) {
        size_t rank = (size_t)(rankbase(ti) + (b - ti));
        S0 += COL[(rank * 3 + 0) * 128 + t];
        S1 += COL[(rank * 3 + 1) * 128 + t];
        S2 += COL[(rank * 3 + 2) * 128 + t];
    }
    float sx = *sxp, sy = *syp, sj = *sjp;
    float logN = logf((float)NROW);
    float lpx = logf(S0) - (float)DD * logf(sx) - 0.5f * (float)DD * LOG_2PI - logN;
    float lpy = logf(S1) - (float)DD * logf(sy) - 0.5f * (float)DD * LOG_2PI - logN;
    float lpj = logf(S2) - 2.0f * (float)DD * logf(sj) - (float)DD * LOG_2PI - logN;
    float I = expf(lpj) * (lpj - lpx - lpy);
#pragma unroll
    for (int m = 1; m < 64; m <<= 1) I += __shfl_xor(I, m, 64);
    __shared__ float w0[2];
    if ((t & 63) == 0) w0[t >> 6] = I;
    __syncthreads();
    if (t == 0) bsum[b] = w0[0] + w0[1];
}

__global__ void final_reduce(const float* __restrict__ bsum, float* __restrict__ out) {
    int t = threadIdx.x;   // 64
    float v = bsum[t];
#pragma unroll
    for (int m = 1; m < 64; m <<= 1) v += __shfl_xor(v, m, 64);
    if (t == 0) out[0] = -v;
}

// ================= FALLBACK (round-2, proven; used only if ws too small) =================
template <bool SAME>
__device__ __forceinline__ void fb_combine(const f32x4 (&ax)[4][2], const f32x4 (&ay)[4][2],
                                           const float (&sq)[4][TS],
                                           float (&rowred)[4][TS][3], float (&colred)[2][TS][3],
                                           int wr, int wc, int lane,
                                           float cx2, float cy2, float cj2) {
    float pcol[2][3] = {{0.f,0.f,0.f},{0.f,0.f,0.f}};
#pragma unroll
    for (int rf = 0; rf < 4; ++rf) {
        float prow[4][3] = {{0.f,0.f,0.f},{0.f,0.f,0.f},{0.f,0.f,0.f},{0.f,0.f,0.f}};
        float sxi[4], syi[4];
#pragma unroll
        for (int reg = 0; reg < 4; ++reg) {
            int row = wr*64 + rf*16 + ((lane>>4)<<2) + reg;
            sxi[reg] = sq[0][row]; syi[reg] = sq[1][row];
        }
#pragma unroll
        for (int cf = 0; cf < 2; ++cf) {
            int col = wc*32 + cf*16 + (lane & 15);
            float qx = sq[2][col], qy = sq[3][col];
#pragma unroll
            for (int reg = 0; reg < 4; ++reg) {
                float gx = ax[rf][cf][reg], gy = ay[rf][cf][reg];
                float d2x = fmaxf(fmaf(-2.f, gx, sxi[reg] + qx), 0.f);
                float d2y = fmaxf(fmaf(-2.f, gy, syi[reg] + qy), 0.f);
                float ex = fexp2(d2x * cx2);
                float ey = fexp2(d2y * cy2);
                float ej = SAME ? (ex * ey) : fexp2(fmaf(d2y, cj2, d2x * cj2));
                prow[reg][0] += ex; prow[reg][1] += ey; prow[reg][2] += ej;
                pcol[cf][0]  += ex; pcol[cf][1]  += ey; pcol[cf][2]  += ej;
            }
        }
#pragma unroll
        for (int reg = 0; reg < 4; ++reg)
#pragma unroll
            for (int ch = 0; ch < 3; ++ch) {
                float v = prow[reg][ch];
                v += __shfl_xor(v, 1, 64); v += __shfl_xor(v, 2, 64);
                v += __shfl_xor(v, 4, 64); v += __shfl_xor(v, 8, 64);
                if ((lane & 15) == 0)
                    rowred[wc][wr*64 + rf*16 + ((lane>>4)<<2) + reg][ch] = v;
            }
    }
#pragma unroll
    for (int cf = 0; cf < 2; ++cf)
#pragma unroll
        for (int ch = 0; ch < 3; ++ch) {
            float v = pcol[cf][ch];
            v += __shfl_xor(v, 16, 64); v += __shfl_xor(v, 32, 64);
            if (lane < 16) colred[wr][wc*32 + cf*16 + lane][ch] = v;
        }
}

__launch_bounds__(BLOCK)
__global__ void kde_fb(const float* __restrict__ X, const float* __restrict__ Y,
                       const float* __restrict__ sjp, const float* __restrict__ sxp,
                       const float* __restrict__ syp,
                       unsigned long long* __restrict__ acc,
                       const float* __restrict__ sqx, const float* __restrict__ sqy) {
    __shared__ unsigned short T[4][TS][DD];
    __shared__ float sq[4][TS];
    __shared__ float rowred[4][TS][3];
    __shared__ float colred[2][TS][3];

    const int tid  = threadIdx.x;
    const int lane = tid & 63;
    const int wid  = tid >> 6;
    const int wr   = wid >> 2;
    const int wc   = wid & 3;

    int b = (blockIdx.x & 7) * (NPAIR / 8) + (blockIdx.x >> 3);
    int ti = 0, rem = b;
    while (rem >= NT - ti) { rem -= NT - ti; ++ti; }
    int tj = ti + rem;
    const int i0 = ti * TS, j0 = tj * TS;

    const float sxv = *sxp, syv = *syp, sjv = *sjp;
    const float cx2 = -0.5f * L2E / (sxv * sxv);
    const float cy2 = -0.5f * L2E / (syv * syv);
    const float cj2 = -0.5f * L2E / (sjv * sjv);
    const bool samesig = (cx2 == cy2) && (cy2 == cj2);

    for (int c = tid; c < 8192; c += BLOCK) {
        int t = c >> 11, row = (c >> 4) & 127, col8 = c & 15;
        const float* base =
            (t == 0) ? X + (size_t)i0 * DD : (t == 1) ? Y + (size_t)i0 * DD :
            (t == 2) ? X + (size_t)j0 * DD : Y + (size_t)j0 * DD;
        const float4* s4 = reinterpret_cast<const float4*>(base + row * DD + col8 * 8);
        float4 a = s4[0], bb = s4[1];
        unsigned int w0 = (unsigned int)f2bf(a.x)  | ((unsigned int)f2bf(a.y)  << 16);
        unsigned int w1 = (unsigned int)f2bf(a.z)  | ((unsigned int)f2bf(a.w)  << 16);
        unsigned int w2 = (unsigned int)f2bf(bb.x) | ((unsigned int)f2bf(bb.y) << 16);
        unsigned int w3 = (unsigned int)f2bf(bb.z) | ((unsigned int)f2bf(bb.w) << 16);
        uint4 pk = make_uint4(w0, w1, w2, w3);
        int sl = (col8 ^ (row & 7)) << 3;
        *reinterpret_cast<uint4*>(&T[t][row][sl]) = pk;
    }
    {
        int t = tid >> 7, r = tid & 127;
        const float* s = (t == 0) ? sqx + i0 : (t == 1) ? sqy + i0
                       : (t == 2) ? sqx + j0 : sqy + j0;
        sq[t][r] = s[r];
    }
    __syncthreads();

    f32x4 ax[4][2], ay[4][2];
#pragma unroll
    for (int rf = 0; rf < 4; ++rf)
#pragma unroll
        for (int cf = 0; cf < 2; ++cf) {
            ax[rf][cf] = (f32x4){0.f,0.f,0.f,0.f};
            ay[rf][cf] = (f32x4){0.f,0.f,0.f,0.f};
        }
#pragma unroll
    for (int kk = 0; kk < 4; ++kk) {
        const int k0 = kk * 4 + (lane >> 4);
        bf16x8 afx[4], afy[4], bfx[2], bfy[2];
#pragma unroll
        for (int rf = 0; rf < 4; ++rf) {
            int r  = wr * 64 + rf * 16 + (lane & 15);
            int sl = (k0 ^ (r & 7)) << 3;
            afx[rf] = *reinterpret_cast<const bf16x8*>(&T[0][r][sl]);
            afy[rf] = *reinterpret_cast<const bf16x8*>(&T[1][r][sl]);
        }
#pragma unroll
        for (int cf = 0; cf < 2; ++cf) {
            int r  = wc * 32 + cf * 16 + (lane & 15);
            int sl = (k0 ^ (r & 7)) << 3;
            bfx[cf] = *reinterpret_cast<const bf16x8*>(&T[2][r][sl]);
            bfy[cf] = *reinterpret_cast<const bf16x8*>(&T[3][r][sl]);
        }
#pragma unroll
        for (int rf = 0; rf < 4; ++rf)
#pragma unroll
            for (int cf = 0; cf < 2; ++cf) {
                ax[rf][cf] = __builtin_amdgcn_mfma_f32_16x16x32_bf16(afx[rf], bfx[cf], ax[rf][cf], 0, 0, 0);
                ay[rf][cf] = __builtin_amdgcn_mfma_f32_16x16x32_bf16(afy[rf], bfy[cf], ay[rf][cf], 0, 0, 0);
            }
    }

    if (samesig) fb_combine<true >(ax, ay, sq, rowred, colred, wr, wc, lane, cx2, cy2, cj2);
    else         fb_combine<false>(ax, ay, sq, rowred, colred, wr, wc, lane, cx2, cy2, cj2);
    __syncthreads();

    if (tid < TS) {
        int r = tid;
#pragma unroll
        for (int ch = 0; ch < 3; ++ch) {
            float v = rowred[0][r][ch] + rowred[1][r][ch] + rowred[2][r][ch] + rowred[3][r][ch];
            atomicAdd(&acc[(size_t)(i0 + r) * 3 + ch],
                      (unsigned long long)(long long)((double)v * FP_SCALE));
        }
    } else if (tid < 2 * TS && ti != tj) {
        int r = tid - TS;
#pragma unroll
        for (int ch = 0; ch < 3; ++ch) {
            float v = colred[0][r][ch] + colred[1][r][ch];
            atomicAdd(&acc[(size_t)(j0 + r) * 3 + ch],
                      (unsigned long long)(long long)((double)v * FP_SCALE));
        }
    }
}

__global__ void lp_fb(const float* __restrict__ sjp, const float* __restrict__ sxp,
                      const float* __restrict__ syp,
                      const unsigned long long* __restrict__ acc,
                      float* __restrict__ bsum) {
    int b = blockIdx.x, t = threadIdx.x;
    size_t row = (size_t)b * 128 + t;
    const double INV = 1.0 / FP_SCALE;
    float S0 = (float)((double)acc[row * 3 + 0] * INV);
    float S1 = (float)((double)acc[row * 3 + 1] * INV);
    float S2 = (float)((double)acc[row * 3 + 2] * INV);
    float sx = *sxp, sy = *syp, sj = *sjp;
    float logN = logf((float)NROW);
    float lpx = logf(S0) - (float)DD * logf(sx) - 0.5f * (float)DD * LOG_2PI - logN;
    float lpy = logf(S1) - (float)DD * logf(sy) - 0.5f * (float)DD * LOG_2PI - logN;
    float lpj = logf(S2) - 2.0f * (float)DD * logf(sj) - (float)DD * LOG_2PI - logN;
    float I = expf(lpj) * (lpj - lpx - lpy);
#pragma unroll
    for (int m = 1; m < 64; m <<= 1) I += __shfl_xor(I, m, 64);
    __shared__ float w0[2];
    if ((t & 63) == 0) w0[t >> 6] = I;
    __syncthreads();
    if (t == 0) bsum[b] = w0[0] + w0[1];
}

extern "C" void kernel_launch(void* const* d_in, const int* in_sizes, int n_in,
                              void* d_out, int out_size, void* d_ws, size_t ws_size,
                              hipStream_t stream) {
    (void)in_sizes; (void)n_in; (void)out_size;
    const float* X  = (const float*)d_in[0];
    const float* Y  = (const float*)d_in[1];
    const float* sj = (const float*)d_in[2];
    const float* sx = (const float*)d_in[3];
    const float* sy = (const float*)d_in[4];
    float* out = (float*)d_out;
    char*  w   = (char*)d_ws;

    unsigned long long* ACC = (unsigned long long*)(w + ACC_B);
    float* SQX  = (float*)(w + SQX_B);
    float* SQY  = (float*)(w + SQY_B);
    float* BSUM = (float*)(w + BSUM_B);
    float* COLS = (float*)(w + COLSLOT_B);
    unsigned short* XB = (unsigned short*)(w + XB_B);
    unsigned short* YB = (unsigned short*)(w + YB_B);

    hipMemsetAsync(w + ACC_B, 0, NROW * 3 * sizeof(unsigned long long), stream);

    if (ws_size >= (size_t)PRIMARY_NEED) {
        sq_kernel<true ><<<dim3(2048), dim3(256), 0, stream>>>(X, Y, SQX, SQY, XB, YB);
        kde_primary<<<dim3(NBLOCKS), dim3(BLOCK), 0, stream>>>(XB, YB, sj, sx, sy, ACC, COLS, SQX, SQY);
        lp_primary<<<dim3(64), dim3(128), 0, stream>>>(sj, sx, sy, ACC, COLS, BSUM);
    } else {
        sq_kernel<false><<<dim3(2048), dim3(256), 0, stream>>>(X, Y, SQX, SQY, XB, YB);
        kde_fb<<<dim3(NPAIR), dim3(BLOCK), 0, stream>>>(X, Y, sj, sx, sy, ACC, SQX, SQY);
        lp_fb<<<dim3(64), dim3(128), 0, stream>>>(sj, sx, sy, ACC, BSUM);
    }
    final_reduce<<<dim3(1), dim3(64), 0, stream>>>(BSUM, out);
}